// Round 15
// baseline (3840.294 us; speedup 1.0000x reference)
//
#include <hip/hip_runtime.h>
#include <hip/hip_bf16.h>

// Problem constants
#define B_   64
#define T_   512
#define I_   512
#define H_   512
#define G_   5
#define NROW 2560   // G*H gate rows per direction
#define KD   512    // K depth

typedef __attribute__((ext_vector_type(8))) __bf16 bf16x8;
typedef __attribute__((ext_vector_type(4))) float  f32x4;
typedef __attribute__((ext_vector_type(2))) unsigned long long u64x2;
typedef unsigned long long u64;

#define MFMA16(A, Bf, C) __builtin_amdgcn_mfma_f32_16x16x32_bf16(A, Bf, C, 0, 0, 0)

__device__ __forceinline__ unsigned short f2bf(float f) {
  unsigned u = __builtin_bit_cast(unsigned, f);
  u = (u + 0x7fffu + ((u >> 16) & 1u)) >> 16;   // RNE
  return (unsigned short)u;
}
__device__ __forceinline__ float bf2f(unsigned short s) {
  unsigned u = ((unsigned)s) << 16;
  return __builtin_bit_cast(float, u);
}
__device__ __forceinline__ float sigm(float x) { return 1.f / (1.f + __expf(-x)); }
__device__ __forceinline__ float tanh_fast(float x) {
  return 1.f - 2.f / (__expf(2.f * x) + 1.f);
}
__device__ __forceinline__ u64 al64(const u64* p) {
  return __hip_atomic_load(p, __ATOMIC_RELAXED, __HIP_MEMORY_SCOPE_AGENT);
}
__device__ __forceinline__ void as64(u64* p, u64 v) {
  __hip_atomic_store(p, v, __ATOMIC_RELAXED, __HIP_MEMORY_SCOPE_AGENT);
}
__device__ __forceinline__ unsigned al32(const unsigned* p) {
  return __hip_atomic_load(p, __ATOMIC_RELAXED, __HIP_MEMORY_SCOPE_AGENT);
}
__device__ __forceinline__ void st32(unsigned* p, unsigned v) {
  __hip_atomic_store(p, v, __ATOMIC_RELAXED, __HIP_MEMORY_SCOPE_AGENT);
}

// ---------------- ws layout (bytes) ----------------
#define OFF_XP   ((size_t)0)
#define OFF_XB   ((size_t)335544320)
#define OFF_W2X  ((size_t)369098752)
#define OFF_W2H  ((size_t)374341632)
#define OFF_BIAS ((size_t)379584512)
#define OFF_HB   ((size_t)379604992)   // L2-domain h: 8 doms x 32KB = 256KB
#define OFF_BAR  ((size_t)379867136)   // u32[1024]: fl_l2[256], fl_mir[256], cnt[8], gcnt
#define OFF_HMIR ((size_t)379871232)   // mirror h: 256KB
#define WS_NEED  ((size_t)380133376)

// ---------------- sentinel (ws too small) ----------------
__global__ void k_sentinel(float* out, int n) {
  int i = blockIdx.x * 256 + threadIdx.x;
  if (i < n) out[i] = 10000.0f;
}

// ---------------- converts ----------------
__global__ void k_cvt_weights(const float* __restrict__ Wx_f, const float* __restrict__ Wh_f,
                              const float* __restrict__ Wx_b, const float* __restrict__ Wh_b,
                              const float* __restrict__ bx_f, const float* __restrict__ bh_f,
                              const float* __restrict__ bx_b, const float* __restrict__ bh_b,
                              unsigned short* __restrict__ W2x, unsigned short* __restrict__ W2h,
                              float* __restrict__ bias2) {
  int idx = blockIdx.x * 256 + threadIdx.x;       // exactly 2*NROW*KD threads
  int dir = idx / (NROW * KD);
  int r   = idx % (NROW * KD);
  W2x[idx] = f2bf(dir ? Wx_b[r] : Wx_f[r]);
  W2h[idx] = f2bf(dir ? Wh_b[r] : Wh_f[r]);
  if (idx < 2 * NROW) {
    int d2 = idx / NROW, n = idx % NROW;
    bias2[idx] = d2 ? (bx_b[n] + bh_b[n]) : (bx_f[n] + bh_f[n]);
  }
}

__global__ void k_cvt_x(const float* __restrict__ x, unsigned short* __restrict__ xb) {
  int idx = blockIdx.x * 256 + threadIdx.x;       // exactly B*T*I threads
  xb[idx] = f2bf(x[idx]);
}

__global__ void k_zero_h(unsigned* __restrict__ h2, unsigned* __restrict__ hm,
                         unsigned* __restrict__ bar) {
  int idx = blockIdx.x * 256 + threadIdx.x;       // 65536 threads
  h2[idx] = 0;                                    // 256KB
  hm[idx] = 0;                                    // 256KB
  if (idx < 1024) bar[idx] = 0;
}

// ---------------- phase 1: xp = Wx · x^T (+bias), both dirs ----------------
__global__ __launch_bounds__(256) void k_gemm_xp(
    const unsigned short* __restrict__ W2x,   // [2][NROW][KD]
    const unsigned short* __restrict__ xb,    // [B][T][I]
    const float* __restrict__ bias2,          // [2][NROW]
    unsigned short* __restrict__ xp)          // [2][T][NROW][B]
{
  const int tid = threadIdx.x;
  const int lane = tid & 63, wv = tid >> 6;
  int bz = blockIdx.x;
  const int dir = bz / (20 * 256); bz %= (20 * 256);
  const int nblk = bz / 256, mblk = bz % 256;
  const int n0 = nblk * 128, m0 = mblk * 128;
  const int l15 = lane & 15, l4 = lane >> 4;
  const int nh = wv >> 1, mh = wv & 1;

  __shared__ unsigned short Al[128 * 72];
  __shared__ unsigned short Bl[128 * 72];

  const unsigned short* Wd = W2x + (size_t)dir * NROW * KD;

  f32x4 acc[4][4];
  f32x4 zz = {0.f, 0.f, 0.f, 0.f};
#pragma unroll
  for (int i = 0; i < 4; ++i)
#pragma unroll
    for (int j = 0; j < 4; ++j) acc[i][j] = zz;

  for (int k0 = 0; k0 < KD; k0 += 64) {
#pragma unroll
    for (int j = 0; j < 4; ++j) {
      int sg = j * 256 + tid;
      int row = sg >> 3, ko = (sg & 7) * 8;
      bf16x8 va = *(const bf16x8*)(Wd + (size_t)(n0 + row) * KD + k0 + ko);
      *(bf16x8*)(Al + row * 72 + ko) = va;
      int m = m0 + row;
      int ss = m >> 6, b = m & 63;
      int trow = dir ? (T_ - 1 - ss) : ss;
      bf16x8 vb = *(const bf16x8*)(xb + ((size_t)b * T_ + trow) * I_ + k0 + ko);
      *(bf16x8*)(Bl + row * 72 + ko) = vb;
    }
    __syncthreads();
#pragma unroll
    for (int kk = 0; kk < 2; ++kk) {
      bf16x8 af[4], bfr[4];
#pragma unroll
      for (int f = 0; f < 4; ++f) {
        af[f]  = *(const bf16x8*)(Al + (nh * 64 + f * 16 + l15) * 72 + kk * 32 + l4 * 8);
        bfr[f] = *(const bf16x8*)(Bl + (mh * 64 + f * 16 + l15) * 72 + kk * 32 + l4 * 8);
      }
#pragma unroll
      for (int fi = 0; fi < 4; ++fi)
#pragma unroll
        for (int fj = 0; fj < 4; ++fj)
          acc[fi][fj] = MFMA16(af[fi], bfr[fj], acc[fi][fj]);
    }
    __syncthreads();
  }

#pragma unroll
  for (int fi = 0; fi < 4; ++fi) {
#pragma unroll
    for (int fj = 0; fj < 4; ++fj) {
#pragma unroll
      for (int r = 0; r < 4; ++r) {
        int n = n0 + nh * 64 + fi * 16 + l4 * 4 + r;
        int m = m0 + mh * 64 + fj * 16 + l15;
        int ss = m >> 6, b = m & 63;
        float v = acc[fi][fj][r] + bias2[dir * NROW + n];
        xp[(((size_t)dir * T_ + ss) * NROW + n) * 64 + b] = f2bf(v);
      }
    }
  }
}

// ---------------- phase 2: XCD-local-domain persistent kernel ----------------
// 256 blocks x 64 threads, ~91.5KB LDS -> forced 1 block/CU -> exactly 32
// blocks per XCD. 8 independent domains = (dir, batch-quarter of 16).
// Good case: domain = XCD (runtime-claimed), h/flags exchanged via XCD-local
// L2 (plain stores + sc0 loads). Producers dual-store to an L3 mirror; any
// poll timeout stickily falls back to the mirror (degrade, not deadlock).
// Balance check after a one-time global barrier guards mis-assignment.
// Per block per step: 16 batches x 80 gate rows, 80 MFMA (R14 wave, proven).
#define GSTEP(CUR, NXT, NT, NP)                                            \
  {                                                                        \
    _Pragma("unroll")                                                      \
    for (int ks = 0; ks < 16; ++ks)                                        \
      NXT[ks] = *(const bf16x8*)(w_lds + ((NP)*16 + l15) * 520 + ks * 32 + l4 * 8); \
    _Pragma("unroll")                                                      \
    for (int ks = 0; ks < 16; ++ks)                                        \
      acc[NT] = MFMA16(ha[ks], CUR[ks], acc[NT]);                          \
  }

__global__ __launch_bounds__(64, 1) void k_recurrent(
    const unsigned short* __restrict__ W2h,  // [2][NROW][KD]
    const unsigned short* __restrict__ xp,   // [2][T][NROW][B]
    unsigned short* __restrict__ hb2,        // L2 domains: [8][2 buf][16 b][512 u]
    unsigned short* __restrict__ hbm,        // L3 mirror, same layout
    float* __restrict__ out,                 // [B][T][2H]
    unsigned* __restrict__ bar)
{
  const int lane = threadIdx.x;
  const int l15 = lane & 15, l4 = lane >> 4;

  __shared__ unsigned short w_lds[80 * 520];   // 83.2 KB
  __shared__ float          gl[16 * 84];       //  5.4 KB
  __shared__ unsigned short xl[80 * 18];       //  2.9 KB

  // ---- discover XCD, claim rank, one-time global barrier, balance check ----
  unsigned xcd;
  asm("s_getreg_b32 %0, hwreg(HW_REG_XCC_ID, 0, 4)" : "=s"(xcd));
  xcd &= 7;
  unsigned rank = 0;
  if (lane == 0) rank = atomicAdd(&bar[512 + xcd], 1u);
  rank = (unsigned)__shfl((int)rank, 0);
  if (lane == 0) atomicAdd(&bar[520], 1u);
  while (al32(&bar[520]) < 256u) __builtin_amdgcn_s_sleep(2);
  bool good = true;
#pragma unroll
  for (int x = 0; x < 8; ++x) good = good && (al32(&bar[512 + x]) == 32u);

  int dom, rk;
  bool l3;
  if (good && rank < 32u) { dom = (int)xcd; rk = (int)rank; l3 = false; }
  else                    { dom = blockIdx.x >> 5; rk = blockIdx.x & 31; l3 = true; }

  const int dir = dom >> 2, bq = dom & 3;      // 16 batches: bq*16..+15
  // my units: rk*16 .. rk*16+15  -> 80 gate rows

  // ---- stage Wh (80 rows x 512) into LDS ----
  for (int it = 0; it < 80; ++it) {
    int seg = it * 64 + lane;
    int r = seg >> 6, c8 = seg & 63;
    const unsigned short* src =
        W2h + ((size_t)dir * NROW + (r >> 4) * H_ + rk * 16 + (r & 15)) * KD + c8 * 8;
    *(bf16x8*)(w_lds + r * 520 + c8 * 8) = *(const bf16x8*)src;
  }

  const unsigned short* xpd = xp + (size_t)dir * T_ * NROW * 64;
  unsigned short* h2d = hb2 + (size_t)dom * 16384;   // ushort units
  unsigned short* hmd = hbm + (size_t)dom * 16384;
  unsigned* fl2 = bar + dom * 32;
  unsigned* flm = bar + 256 + dom * 32;

  const int bl = lane >> 2, uq = (lane & 3) * 4;     // cells: batch bl, units uq..+3
  float kst[4] = {0.f, 0.f, 0.f, 0.f}, kp[4] = {0.f, 0.f, 0.f, 0.f};

  unsigned xr[10];
  auto ld_xp = [&](int s) {
    const unsigned* x32 = (const unsigned*)(xpd + (size_t)s * NROW * 64);
#pragma unroll
    for (int j = 0; j < 10; ++j) {
      int id = j * 64 + lane;
      int rl = id >> 3, c = id & 7;
      xr[j] = x32[((size_t)(rl >> 4) * H_ + rk * 16 + (rl & 15)) * 32 + bq * 8 + c];
    }
  };
  ld_xp(0);

  f32x4 zz = {0.f, 0.f, 0.f, 0.f};
  bf16x8 wfA[16], wfB[16];
#pragma unroll
  for (int ks = 0; ks < 16; ++ks)
    wfA[ks] = *(const bf16x8*)(w_lds + l15 * 520 + ks * 32 + l4 * 8);

  auto body = [&](int s, bf16x8 (&cw)[16], bf16x8 (&nw)[16]) {
    if (s) {
      __builtin_amdgcn_sched_barrier(0);
      unsigned tgt = (unsigned)s;
      if (!l3) {
        int spins = 0;
        for (;;) {
          unsigned v;
          asm volatile("global_load_dword %0, %1, off sc0\n\ts_waitcnt vmcnt(0)"
                       : "=v"(v) : "v"(fl2 + (lane & 31)) : "memory");
          if (!__any(v < tgt)) break;
          if (++spins > 16384) { l3 = true; break; }   // sticky L3 fallback
          __builtin_amdgcn_s_sleep(1);
        }
      }
      if (l3) {
        for (;;) {
          unsigned v = al32(flm + (lane & 31));
          if (!__any(v < tgt)) break;
          __builtin_amdgcn_s_sleep(1);
        }
      }
      __builtin_amdgcn_sched_barrier(0);
    }

    // h A-frag loads: h[b=l15][u = ks*32 + l4*8 ..+8], 16B each
    bf16x8 ha[16];
    {
      const unsigned short* hq =
          (l3 ? hmd : h2d) + (s & 1) * 8192 + l15 * 512 + l4 * 8;
      if (!l3) {
#pragma unroll
        for (int ks = 0; ks < 16; ++ks)
          asm volatile("global_load_dwordx4 %0, %1, off sc0"
                       : "=v"(ha[ks]) : "v"(hq + ks * 32));
        asm volatile("s_waitcnt vmcnt(0)" ::: "memory");
        __builtin_amdgcn_sched_barrier(0);
      } else {
#pragma unroll
        for (int ks = 0; ks < 16; ++ks) {
          u64 lo = al64((const u64*)(hq + ks * 32));
          u64 hi = al64((const u64*)(hq + ks * 32) + 1);
          u64x2 t2 = {lo, hi};
          ha[ks] = __builtin_bit_cast(bf16x8, t2);
        }
      }
    }

    // commit xp (loaded pre-poll) into strip
#pragma unroll
    for (int j = 0; j < 10; ++j) {
      int id = j * 64 + lane;
      int rl = id >> 3, c = id & 7;
      *(unsigned*)(xl + rl * 18 + c * 2) = xr[j];
    }

    // 80 MFMA: 5 N-tiles, weight frags double-buffered from LDS
    f32x4 acc[5] = {zz, zz, zz, zz, zz};
    GSTEP(cw, nw, 0, 1)
    GSTEP(nw, cw, 1, 2)
    GSTEP(cw, nw, 2, 3)
    GSTEP(nw, cw, 3, 4)
    GSTEP(cw, nw, 4, 0)

    // dump gates: row = batch (l4*4+rr), col = gate row (nt*16+l15)
#pragma unroll
    for (int Nt = 0; Nt < 5; ++Nt)
#pragma unroll
      for (int rr = 0; rr < 4; ++rr)
        gl[(l4 * 4 + rr) * 84 + Nt * 16 + l15] = acc[Nt][rr];
    asm volatile("s_waitcnt lgkmcnt(0)" ::: "memory");
    __builtin_amdgcn_sched_barrier(0);

    // cell update: 4 cells (batch bl, units uq..uq+3)
    float hv[4];
#pragma unroll
    for (int j = 0; j < 4; ++j) {
      int u = uq + j;
      float g0 = gl[bl * 84 + 0 * 16 + u] + bf2f(xl[(0 * 16 + u) * 18 + bl]);
      float g1 = gl[bl * 84 + 1 * 16 + u] + bf2f(xl[(1 * 16 + u) * 18 + bl]);
      float g2 = gl[bl * 84 + 2 * 16 + u] + bf2f(xl[(2 * 16 + u) * 18 + bl]);
      float g3 = gl[bl * 84 + 3 * 16 + u] + bf2f(xl[(3 * 16 + u) * 18 + bl]);
      float g4 = gl[bl * 84 + 4 * 16 + u] + bf2f(xl[(4 * 16 + u) * 18 + bl]);
      float ff = sigm(g0), ii = sigm(g1), oo = sigm(g2), uu = sigm(g3), tk = tanh_fast(g4);
      kp[j]  = uu * tk + (1.f - uu) * kp[j];
      kst[j] = ff * kst[j] + ii * kp[j];
      hv[j]  = oo * tanh_fast(kst[j]);
    }

    // publish h: dual store (plain -> domain L2; agent -> L3 mirror)
    u64 hw = (u64)f2bf(hv[0]) | ((u64)f2bf(hv[1]) << 16) |
             ((u64)f2bf(hv[2]) << 32) | ((u64)f2bf(hv[3]) << 48);
    {
      size_t off = (size_t)((s + 1) & 1) * 8192 + bl * 512 + rk * 16 + uq;
      asm volatile("global_store_dwordx2 %0, %1, off"
                   :: "v"(h2d + off), "v"(hw) : "memory");
      as64((u64*)(hmd + off), hw);
    }

    int tout = dir ? (T_ - 1 - s) : s;
    float4 o4 = {hv[0], hv[1], hv[2], hv[3]};
    if (s + 1 < T_) {
      asm volatile("s_waitcnt vmcnt(0)" ::: "memory");   // both h stores acked
      if (lane == 0) {
        unsigned nf = (unsigned)(s + 1);
        asm volatile("global_store_dword %0, %1, off"
                     :: "v"(fl2 + rk), "v"(nf) : "memory");
        st32(flm + rk, nf);
      }
      *(float4*)&out[((size_t)(bq * 16 + bl) * T_ + tout) * (2 * H_) +
                     dir * H_ + rk * 16 + uq] = o4;
      ld_xp(s + 1);
    } else {
      *(float4*)&out[((size_t)(bq * 16 + bl) * T_ + tout) * (2 * H_) +
                     dir * H_ + rk * 16 + uq] = o4;
    }
  };

  for (int s = 0; s < T_; s += 2) {
    body(s,     wfA, wfB);
    body(s + 1, wfB, wfA);
  }
}

// ---------------- launch ----------------
extern "C" void kernel_launch(void* const* d_in, const int* in_sizes, int n_in,
                              void* d_out, int out_size, void* d_ws, size_t ws_size,
                              hipStream_t stream) {
  const float* x    = (const float*)d_in[0];
  const float* Wx_f = (const float*)d_in[1];
  const float* bx_f = (const float*)d_in[2];
  const float* Wh_f = (const float*)d_in[3];
  const float* bh_f = (const float*)d_in[4];
  const float* Wx_b = (const float*)d_in[5];
  const float* bx_b = (const float*)d_in[6];
  const float* Wh_b = (const float*)d_in[7];
  const float* bh_b = (const float*)d_in[8];
  float* out = (float*)d_out;

  if (ws_size < WS_NEED) {
    k_sentinel<<<(out_size + 255) / 256, 256, 0, stream>>>(out, out_size);
    return;
  }

  char* ws = (char*)d_ws;
  unsigned short* xp    = (unsigned short*)(ws + OFF_XP);
  unsigned short* xb    = (unsigned short*)(ws + OFF_XB);
  unsigned short* W2x   = (unsigned short*)(ws + OFF_W2X);
  unsigned short* W2h   = (unsigned short*)(ws + OFF_W2H);
  float*          bias2 = (float*)(ws + OFF_BIAS);
  unsigned short* hb2   = (unsigned short*)(ws + OFF_HB);
  unsigned*       bar   = (unsigned*)(ws + OFF_BAR);
  unsigned short* hbm   = (unsigned short*)(ws + OFF_HMIR);

  k_cvt_weights<<<(2 * NROW * KD) / 256, 256, 0, stream>>>(
      Wx_f, Wh_f, Wx_b, Wh_b, bx_f, bh_f, bx_b, bh_b, W2x, W2h, bias2);
  k_cvt_x<<<(B_ * T_ * I_) / 256, 256, 0, stream>>>(x, xb);
  k_zero_h<<<256, 256, 0, stream>>>((unsigned*)hb2, (unsigned*)hbm, bar);
  k_gemm_xp<<<2 * 20 * 256, 256, 0, stream>>>(W2x, xb, bias2, xp);
  k_recurrent<<<256, 64, 0, stream>>>(W2h, xp, hb2, hbm, out, bar);
}